// Round 3
// baseline (768.284 us; speedup 1.0000x reference)
//
#include <hip/hip_runtime.h>

typedef _Float16 half8 __attribute__((ext_vector_type(8)));
typedef float f32x4 __attribute__((ext_vector_type(4)));

// async global->LDS 16B: LDS dest must be wave-uniform base + lane*16.
__device__ __forceinline__ void gl2lds16(const _Float16* g, _Float16* l) {
  __builtin_amdgcn_global_load_lds((const __attribute__((address_space(1))) void*)g,
                                   (__attribute__((address_space(3))) void*)l, 16, 0, 0);
}

// ---------------- fp32 -> fp16 convert ----------------
__global__ __launch_bounds__(256) void cvt_kernel(const float* __restrict__ in,
                                                  _Float16* __restrict__ out, int n) {
  int i = (blockIdx.x * 256 + threadIdx.x) * 8;
  if (i >= n) return;
  float4 a = *(const float4*)(in + i);
  float4 b = *(const float4*)(in + i + 4);
  half8 o;
  o[0] = (_Float16)a.x; o[1] = (_Float16)a.y; o[2] = (_Float16)a.z; o[3] = (_Float16)a.w;
  o[4] = (_Float16)b.x; o[5] = (_Float16)b.y; o[6] = (_Float16)b.z; o[7] = (_Float16)b.w;
  *(half8*)(out + i) = o;
}

// ---------- fp32 [K][N] -> fp16 [N][K] transpose+convert, 64x64 tiles ----------
__global__ __launch_bounds__(256) void cvtT_kernel(const float* __restrict__ in,
                                                   _Float16* __restrict__ out,
                                                   int K, int N) {
  __shared__ float Ts[64][65];
  const int k0 = blockIdx.y * 64, n0 = blockIdx.x * 64;
  const int t = threadIdx.x;
  const int r = t >> 4, c = (t & 15) * 4;
#pragma unroll
  for (int i = 0; i < 4; i++) {
    float4 v = *(const float4*)(in + (size_t)(k0 + r + i * 16) * N + n0 + c);
    Ts[r + i * 16][c] = v.x; Ts[r + i * 16][c + 1] = v.y;
    Ts[r + i * 16][c + 2] = v.z; Ts[r + i * 16][c + 3] = v.w;
  }
  __syncthreads();
  const int nl = t >> 2, kq = (t & 3) * 16;
  half8 o0, o1;
#pragma unroll
  for (int j = 0; j < 8; j++) {
    o0[j] = (_Float16)Ts[kq + j][nl];
    o1[j] = (_Float16)Ts[kq + 8 + j][nl];
  }
  *(half8*)(out + (size_t)(n0 + nl) * K + k0 + kq) = o0;
  *(half8*)(out + (size_t)(n0 + nl) * K + k0 + kq + 8) = o1;
}

// ---------- V [bh][s][64] -> V^T [bh][64][s] fp16 transpose, 64x64 tiles ----------
__global__ __launch_bounds__(256) void vtrans_kernel(const _Float16* __restrict__ v,
                                                     _Float16* __restrict__ vt) {
  __shared__ _Float16 Ht[64][72];
  const int s0 = blockIdx.x * 64;
  const _Float16* vb = v + (size_t)blockIdx.y * 131072;
  _Float16* vtb = vt + (size_t)blockIdx.y * 131072;
  const int t = threadIdx.x;
  const int sl = t >> 3, dq = (t & 7) * 8;
  *(half8*)&Ht[sl][dq] = *(const half8*)(vb + (s0 + sl) * 64 + dq);
  *(half8*)&Ht[sl + 32][dq] = *(const half8*)(vb + (s0 + sl + 32) * 64 + dq);
  __syncthreads();
  const int dl = t >> 2, sq = (t & 3) * 16;
  half8 o0, o1;
#pragma unroll
  for (int j = 0; j < 8; j++) {
    o0[j] = Ht[sq + j][dl];
    o1[j] = Ht[sq + 8 + j][dl];
  }
  *(half8*)(vtb + (size_t)dl * 2048 + s0 + sq) = o0;
  *(half8*)(vtb + (size_t)dl * 2048 + s0 + sq + 8) = o1;
}

// ---------------- m97-style f16 MFMA GEMM, B pre-transposed [N][K] ----------------
template <int MODE, int BN>
__global__ __launch_bounds__(256) void gemm16(const _Float16* __restrict__ A,
                                              const _Float16* __restrict__ B,
                                              float* __restrict__ Cf,
                                              _Float16* __restrict__ Ch,
                                              int M, int N, int K) {
  constexpr int MI = (BN == 128) ? 4 : 2;
  __shared__ __align__(16) _Float16 As[128 * 32];
  __shared__ __align__(16) _Float16 Bs[BN * 32];
  const int tid = threadIdx.x;
  const int lane = tid & 63;
  const int wid = tid >> 6;
  const int quad = lane >> 4;
  const int l16 = lane & 15;
  const int mbase = (BN == 128) ? (wid >> 1) * 64 : wid * 32;
  const int nbase = (BN == 128) ? (wid & 1) * 64 : 0;
  const int m0 = blockIdx.y * 128;
  const int n0 = blockIdx.x * BN;

  f32x4 acc[MI][4];
  const f32x4 fz = {0.f, 0.f, 0.f, 0.f};
#pragma unroll
  for (int i = 0; i < MI; i++)
#pragma unroll
    for (int j = 0; j < 4; j++) acc[i][j] = fz;

  const int srow = tid >> 2;
  const int kq = (tid & 3) * 8;

  for (int kt = 0; kt < K; kt += 32) {
    gl2lds16(A + (size_t)(m0 + srow) * K + kt + kq, &As[tid * 8]);
    gl2lds16(A + (size_t)(m0 + 64 + srow) * K + kt + kq, &As[2048 + tid * 8]);
    gl2lds16(B + (size_t)(n0 + srow) * K + kt + kq, &Bs[tid * 8]);
    if (BN == 128)
      gl2lds16(B + (size_t)(n0 + 64 + srow) * K + kt + kq, &Bs[2048 + tid * 8]);
    __syncthreads();
    half8 af[MI], bf[4];
#pragma unroll
    for (int mi = 0; mi < MI; mi++)
      af[mi] = *(const half8*)&As[(mbase + mi * 16 + l16) * 32 + quad * 8];
#pragma unroll
    for (int ni = 0; ni < 4; ni++)
      bf[ni] = *(const half8*)&Bs[(nbase + ni * 16 + l16) * 32 + quad * 8];
#pragma unroll
    for (int mi = 0; mi < MI; mi++)
#pragma unroll
      for (int ni = 0; ni < 4; ni++)
        acc[mi][ni] = __builtin_amdgcn_mfma_f32_16x16x32_f16(af[mi], bf[ni], acc[mi][ni], 0, 0, 0);
    __syncthreads();
  }

#pragma unroll
  for (int mi = 0; mi < MI; mi++)
#pragma unroll
    for (int ni = 0; ni < 4; ni++)
#pragma unroll
      for (int r = 0; r < 4; r++) {
        int row = m0 + mbase + mi * 16 + quad * 4 + r;
        int col = n0 + nbase + ni * 16 + l16;
        float v = acc[mi][ni][r];
        if (MODE == 0) {
          Cf[(size_t)row * N + col] = v;
        } else {
          int which = col >> 10, h = (col >> 6) & 15, d = col & 63;
          int b = row >> 11, s = row & 2047;
          Ch[((((size_t)(which * 2 + b) * 16 + h) * 2048) + s) * 64 + d] = (_Float16)v;
        }
      }
}

// ---------------- fused causal attention, no-max softmax ----------------
// heavy-first qt, zero-fill hoisted, 2 k-tiles/iter in pass 1,
// w stored via Ps round-trip as dwordx4.
__global__ __launch_bounds__(256) void attn_kernel(const _Float16* __restrict__ qkv,
                                                   const _Float16* __restrict__ vt,
                                                   float* __restrict__ w_out,
                                                   _Float16* __restrict__ o_buf) {
  const int qt = 31 - blockIdx.x;  // heavy blocks dispatched first
  const int bh = blockIdx.y;
  const int tid = threadIdx.x;
  const int lane = tid & 63;
  const int wid = tid >> 6;
  const int quad = lane >> 4;
  const int l16 = lane & 15;

  const _Float16* qp = qkv + (size_t)bh * 131072;
  const _Float16* kp = qp + 4194304;
  const _Float16* vtb = vt + (size_t)bh * 131072;

  __shared__ __align__(16) _Float16 Ks[2 * 64 * 32];
  __shared__ __align__(16) _Float16 Vs[2 * 64 * 32];
  __shared__ __align__(16) _Float16 Ps[64][72];

  float* wbase = w_out + (size_t)bh * 4194304 + (size_t)qt * 64 * 2048;
  const f32x4 fz = {0.f, 0.f, 0.f, 0.f};

  // ---- upper-triangle zeros first: no deps, writes overlap later compute ----
  {
    const int zrow = tid >> 2;
    float* zr = wbase + (size_t)zrow * 2048;
    for (int c = (qt + 1) * 64 + (tid & 3) * 4; c < 2048; c += 16)
      *(f32x4*)(zr + c) = fz;
  }

  const int qrow = qt * 64 + wid * 16 + l16;
  const half8 qa0 = *(const half8*)(qp + qrow * 64 + quad * 8);
  const half8 qa1 = *(const half8*)(qp + qrow * 64 + 32 + quad * 8);

  const int srow = tid >> 2;
  const int blk8 = (tid & 3) * 8;
  const float sc = 0.125f;
  const int lrow0 = wid * 16 + quad * 4;
  const int grow0 = qt * 64 + lrow0;

  float lsum[4] = {0.f, 0.f, 0.f, 0.f};

  // ---- pass 1: l = sum exp(s), two k-tiles per barrier pair ----
  int kt = 0;
  while (kt <= qt) {
    const bool two = (kt + 1 <= qt);
    gl2lds16(kp + (size_t)(kt * 64 + srow) * 64 + blk8, &Ks[tid * 8]);
    gl2lds16(kp + (size_t)(kt * 64 + srow) * 64 + 32 + blk8, &Ks[2048 + tid * 8]);
    if (two) {
      gl2lds16(kp + (size_t)((kt + 1) * 64 + srow) * 64 + blk8, &Vs[tid * 8]);
      gl2lds16(kp + (size_t)((kt + 1) * 64 + srow) * 64 + 32 + blk8, &Vs[2048 + tid * 8]);
    }
    __syncthreads();
#pragma unroll
    for (int half = 0; half < 2; half++) {
      if (half == 1 && !two) break;
      const _Float16* buf = (half == 0) ? Ks : Vs;
      const int tk = kt + half;
#pragma unroll
      for (int ni = 0; ni < 4; ni++) {
        half8 kb0 = *(const half8*)&buf[(ni * 16 + l16) * 32 + quad * 8];
        half8 kb1 = *(const half8*)&buf[2048 + (ni * 16 + l16) * 32 + quad * 8];
        f32x4 s = fz;
        s = __builtin_amdgcn_mfma_f32_16x16x32_f16(qa0, kb0, s, 0, 0, 0);
        s = __builtin_amdgcn_mfma_f32_16x16x32_f16(qa1, kb1, s, 0, 0, 0);
        const int gcol = tk * 64 + ni * 16 + l16;
#pragma unroll
        for (int r = 0; r < 4; r++)
          lsum[r] += (gcol <= grow0 + r) ? __expf(s[r] * sc) : 0.f;
      }
    }
    __syncthreads();
    kt += two ? 2 : 1;
  }
  float invl[4];
#pragma unroll
  for (int r = 0; r < 4; r++) {
    float s = lsum[r];
    s += __shfl_xor(s, 1); s += __shfl_xor(s, 2);
    s += __shfl_xor(s, 4); s += __shfl_xor(s, 8);
    invl[r] = 1.0f / s;
  }

  f32x4 oacc[4];
#pragma unroll
  for (int di = 0; di < 4; di++) oacc[di] = fz;

  // ---- pass 2: recompute S, P->Ps (fp16), PV MFMA, vectorized w store ----
  for (int kt2 = 0; kt2 <= qt; kt2++) {
    gl2lds16(kp + (size_t)(kt2 * 64 + srow) * 64 + blk8, &Ks[tid * 8]);
    gl2lds16(kp + (size_t)(kt2 * 64 + srow) * 64 + 32 + blk8, &Ks[2048 + tid * 8]);
    gl2lds16(vtb + (size_t)srow * 2048 + kt2 * 64 + blk8, &Vs[tid * 8]);
    gl2lds16(vtb + (size_t)srow * 2048 + kt2 * 64 + 32 + blk8, &Vs[2048 + tid * 8]);
    __syncthreads();
#pragma unroll
    for (int ni = 0; ni < 4; ni++) {
      half8 kb0 = *(const half8*)&Ks[(ni * 16 + l16) * 32 + quad * 8];
      half8 kb1 = *(const half8*)&Ks[2048 + (ni * 16 + l16) * 32 + quad * 8];
      f32x4 s = fz;
      s = __builtin_amdgcn_mfma_f32_16x16x32_f16(qa0, kb0, s, 0, 0, 0);
      s = __builtin_amdgcn_mfma_f32_16x16x32_f16(qa1, kb1, s, 0, 0, 0);
      const int gcol = kt2 * 64 + ni * 16 + l16;
#pragma unroll
      for (int r = 0; r < 4; r++) {
        float p = (gcol <= grow0 + r) ? __expf(s[r] * sc) * invl[r] : 0.f;
        Ps[lrow0 + r][ni * 16 + l16] = (_Float16)p;
      }
    }
    __syncthreads();
#pragma unroll
    for (int kk = 0; kk < 2; kk++) {
      half8 pa = *(const half8*)&Ps[wid * 16 + l16][kk * 32 + quad * 8];
#pragma unroll
      for (int di = 0; di < 4; di++) {
        half8 vb = *(const half8*)&Vs[kk * 2048 + (di * 16 + l16) * 32 + quad * 8];
        oacc[di] = __builtin_amdgcn_mfma_f32_16x16x32_f16(pa, vb, oacc[di], 0, 0, 0);
      }
    }
    // coalesced w store: each lane reads 16 fp16 from one Ps row, writes 4x dwordx4
    {
      const int wrow = tid >> 2;
      const int wcol = (tid & 3) * 16;
      half8 h0 = *(const half8*)&Ps[wrow][wcol];
      half8 h1 = *(const half8*)&Ps[wrow][wcol + 8];
      float* dst = wbase + (size_t)wrow * 2048 + kt2 * 64 + wcol;
      f32x4 f0 = {(float)h0[0], (float)h0[1], (float)h0[2], (float)h0[3]};
      f32x4 f1 = {(float)h0[4], (float)h0[5], (float)h0[6], (float)h0[7]};
      f32x4 f2 = {(float)h1[0], (float)h1[1], (float)h1[2], (float)h1[3]};
      f32x4 f3 = {(float)h1[4], (float)h1[5], (float)h1[6], (float)h1[7]};
      *(f32x4*)dst = f0;
      *(f32x4*)(dst + 4) = f1;
      *(f32x4*)(dst + 8) = f2;
      *(f32x4*)(dst + 12) = f3;
    }
    __syncthreads();
  }

  const int b = bh >> 4, h = bh & 15;
#pragma unroll
  for (int di = 0; di < 4; di++)
#pragma unroll
    for (int r = 0; r < 4; r++) {
      int s = qt * 64 + lrow0 + r;
      int d = di * 16 + l16;
      o_buf[((size_t)(b * 2048 + s) * 16 + h) * 64 + d] = (_Float16)oacc[di][r];
    }
}

extern "C" void kernel_launch(void* const* d_in, const int* in_sizes, int n_in,
                              void* d_out, int out_size, void* d_ws, size_t ws_size,
                              hipStream_t stream) {
  const float* x = (const float*)d_in[0];
  const float* w_qkv = (const float*)d_in[1];
  const float* w_proj = (const float*)d_in[2];
  float* out = (float*)d_out;
  float* w_attn = out + (size_t)4194304;

  char* ws = (char*)d_ws;
  _Float16* x16 = (_Float16*)ws;
  _Float16* wqkvT = (_Float16*)(ws + (size_t)(8 << 20));
  _Float16* wprojT = (_Float16*)(ws + (size_t)(14 << 20));
  _Float16* qkvb = (_Float16*)(ws + (size_t)(16 << 20));
  _Float16* vT = (_Float16*)(ws + (size_t)(40 << 20));
  _Float16* ob = (_Float16*)(ws + (size_t)(48 << 20));

  cvt_kernel<<<2048, 256, 0, stream>>>(x, x16, 4194304);
  cvtT_kernel<<<dim3(48, 16), 256, 0, stream>>>(w_qkv, wqkvT, 1024, 3072);
  cvtT_kernel<<<dim3(16, 16), 256, 0, stream>>>(w_proj, wprojT, 1024, 1024);

  gemm16<1, 128><<<dim3(24, 32), 256, 0, stream>>>(x16, wqkvT, nullptr, qkvb, 4096, 3072, 1024);
  vtrans_kernel<<<dim3(32, 32), 256, 0, stream>>>(qkvb + (size_t)2 * 4194304, vT);
  attn_kernel<<<dim3(32, 32), 256, 0, stream>>>(qkvb, vT, w_attn, ob);
  gemm16<0, 64><<<dim3(16, 32), 256, 0, stream>>>(ob, wprojT, out, nullptr, 4096, 1024, 1024);
}